// Round 1
// baseline (341.499 us; speedup 1.0000x reference)
//
#include <hip/hip_runtime.h>
#include <stdint.h>

// Bert4Argument: out[b,l,c] = sum_f feat[b,l,f] * W[c,f] + b[c]
// feat = [ seq[i, head[i,l], :] | pos_emb[l - pos[i] + 256, :] | class_emb[(l==pos[i])?frame[i]:0, :] ]
// B=64, L=256, D=768 -> M=16384, K=2304, N=200 (padded to 208 = 13 tiles of 16)
// Strategy: bf16 MFMA (16x16x32), feat built on the fly in registers; W pre-packed
// to bf16 fragment-contiguous tiles in d_ws.

typedef __attribute__((ext_vector_type(8))) short short8;
typedef __attribute__((ext_vector_type(4))) float floatx4;
typedef __attribute__((ext_vector_type(4))) float f32x4;

__device__ __forceinline__ unsigned short f2bf(float f) {
    union { float f; unsigned int u; } v; v.f = f;
    unsigned int u = v.u;
    // round-to-nearest-even bf16
    return (unsigned short)((u + 0x7fffu + ((u >> 16) & 1u)) >> 16);
}

__device__ __forceinline__ short8 pack8(f32x4 a, f32x4 b) {
    short8 r;
    r[0] = (short)f2bf(a.x); r[1] = (short)f2bf(a.y);
    r[2] = (short)f2bf(a.z); r[3] = (short)f2bf(a.w);
    r[4] = (short)f2bf(b.x); r[5] = (short)f2bf(b.y);
    r[6] = (short)f2bf(b.z); r[7] = (short)f2bf(b.w);
    return r;
}

// ---------------------------------------------------------------------------
// Kernel 1: pack W f32 [200][2304] -> bf16 tiled layout in ws.
// Layout: Wp[(((t*288 + kb8)*16 + n)*8 + j)] = W[t*16+n][kb8*8+j]
//   t  in [0,13)  : n-tile of 16 (rows 200..207 zero-padded)
//   kb8 in [0,288): k-block of 8
// A B-fragment read (fixed t, k0=32-aligned) is then:
//   lane(quad,n): 16B at base + (k0/8 + quad)*256B + n*16B  -> 1KB contiguous/wave
// ---------------------------------------------------------------------------
__global__ void cvt_w_kernel(const float* __restrict__ W,
                             unsigned short* __restrict__ Wp) {
    int u = blockIdx.x * 256 + threadIdx.x;          // [0, 13*288*16) = [0, 59904)
    int n   = u & 15;
    int kb8 = (u >> 4) % 288;
    int t   = u / (288 * 16);
    int row = t * 16 + n;
    int col = kb8 * 8;
    f32x4 a = {0.f, 0.f, 0.f, 0.f}, b = {0.f, 0.f, 0.f, 0.f};
    if (row < 200) {
        const float* p = W + (size_t)row * 2304 + col;
        a = *(const f32x4*)p;
        b = *(const f32x4*)(p + 4);
    }
    short8 s = pack8(a, b);
    *(short8*)(Wp + (size_t)u * 8) = s;
}

// ---------------------------------------------------------------------------
// Kernel 2: GEMM. Block = 256 thr = 4 waves. Wave w -> 16-row m-tile, 13 n-tiles.
// Grid = 256 blocks (M/64).
// ---------------------------------------------------------------------------
__global__ __launch_bounds__(256) void gemm_kernel(
    const float* __restrict__ seq,   // [64,256,768]
    const float* __restrict__ pe,    // [513,768]
    const float* __restrict__ ce,    // [201,768]
    const float* __restrict__ Wf,    // [200,2304] f32 (fallback path)
    const float* __restrict__ bias,  // [200]
    const int*   __restrict__ head,  // [64,256]
    const int*   __restrict__ frame, // [64]
    const int*   __restrict__ pos,   // [64]
    const unsigned short* __restrict__ Wp,  // packed bf16 W or null
    float* __restrict__ out)         // [16384,200]
{
    const int tid  = threadIdx.x;
    const int wave = tid >> 6;
    const int lane = tid & 63;
    const int n16  = lane & 15;
    const int quad = lane >> 4;

    // Feat row this lane supplies to the A operand: m = lane&15 within tile.
    const int mrow  = blockIdx.x * 64 + wave * 16 + n16;   // == i*256 + j
    const int i     = mrow >> 8;
    const int j     = mrow & 255;
    const int pos_i = pos[i];
    const int hi    = head[mrow];
    const int rel   = j - pos_i + 256;                      // in [1,511]
    const int cls   = (j == pos_i) ? frame[i] : 0;

    // per-lane source row base pointers for the 3 feat segments, pre-offset by quad*8
    const float* segs[3];
    segs[0] = seq + ((size_t)i * 256 + (size_t)hi) * 768 + quad * 8;
    segs[1] = pe + (size_t)rel * 768 + quad * 8;
    segs[2] = ce + (size_t)cls * 768 + quad * 8;

    // accumulators initialized with bias (bias depends only on col = n)
    floatx4 acc[13];
#pragma unroll
    for (int t = 0; t < 13; ++t) {
        const int col = t * 16 + n16;
        const float bv = (col < 200) ? bias[col] : 0.0f;
        acc[t] = (floatx4){bv, bv, bv, bv};
    }

    if (Wp) {
        // per-lane fragment base pointers into packed W (16B-aligned)
        const unsigned short* wp[13];
#pragma unroll
        for (int t = 0; t < 13; ++t)
            wp[t] = Wp + (size_t)t * 36864 + (size_t)quad * 128 + (size_t)n16 * 8;

        for (int s = 0; s < 3; ++s) {
            const float* ap = segs[s];
#pragma unroll 2
            for (int kk = 0; kk < 768; kk += 32) {
                f32x4 a0 = *(const f32x4*)(ap + kk);
                f32x4 a1 = *(const f32x4*)(ap + kk + 4);
                short8 afr = pack8(a0, a1);
                const int koff = (s * 768 + kk) * 16;   // ushort offset: (k0/8)*128
#pragma unroll
                for (int t = 0; t < 13; ++t) {
                    short8 bfr = *(const short8*)(wp[t] + koff);
                    acc[t] = __builtin_amdgcn_mfma_f32_16x16x32_bf16(afr, bfr, acc[t], 0, 0, 0);
                }
            }
        }
    } else {
        // fallback: read f32 W and convert inline
        for (int s = 0; s < 3; ++s) {
            const float* ap = segs[s];
            for (int kk = 0; kk < 768; kk += 32) {
                f32x4 a0 = *(const f32x4*)(ap + kk);
                f32x4 a1 = *(const f32x4*)(ap + kk + 4);
                short8 afr = pack8(a0, a1);
                const int kglob = s * 768 + kk + quad * 8;
#pragma unroll
                for (int t = 0; t < 13; ++t) {
                    const int row = t * 16 + n16;
                    short8 bfr = {0, 0, 0, 0, 0, 0, 0, 0};
                    if (row < 200) {
                        const float* q = Wf + (size_t)row * 2304 + kglob;
                        f32x4 b0 = *(const f32x4*)q;
                        f32x4 b1 = *(const f32x4*)(q + 4);
                        bfr = pack8(b0, b1);
                    }
                    acc[t] = __builtin_amdgcn_mfma_f32_16x16x32_bf16(afr, bfr, acc[t], 0, 0, 0);
                }
            }
        }
    }

    // epilogue: C/D layout col = lane&15, row = quad*4 + r
    const int rbase = blockIdx.x * 64 + wave * 16 + quad * 4;
#pragma unroll
    for (int t = 0; t < 13; ++t) {
        const int col = t * 16 + n16;
        if (col < 200) {
#pragma unroll
            for (int r = 0; r < 4; ++r) {
                out[(size_t)(rbase + r) * 200 + col] = acc[t][r];
            }
        }
    }
}

// ---------------------------------------------------------------------------
extern "C" void kernel_launch(void* const* d_in, const int* in_sizes, int n_in,
                              void* d_out, int out_size, void* d_ws, size_t ws_size,
                              hipStream_t stream) {
    const float* seq  = (const float*)d_in[0];
    const float* pe   = (const float*)d_in[1];
    const float* ce   = (const float*)d_in[2];
    const float* W    = (const float*)d_in[3];
    const float* bias = (const float*)d_in[4];
    const int* head   = (const int*)d_in[5];
    const int* frame  = (const int*)d_in[6];
    const int* pos    = (const int*)d_in[7];
    float* out = (float*)d_out;

    const size_t need = (size_t)13 * 288 * 16 * 8 * sizeof(unsigned short); // 958464 B
    unsigned short* Wp = nullptr;
    if (d_ws != nullptr && ws_size >= need) {
        Wp = (unsigned short*)d_ws;
        cvt_w_kernel<<<234, 256, 0, stream>>>(W, Wp);  // 234*256 = 59904 threads
    }
    gemm_kernel<<<256, 256, 0, stream>>>(seq, pe, ce, W, bias, head, frame, pos,
                                         Wp, out);
}

// Round 2
// 179.094 us; speedup vs baseline: 1.9068x; 1.9068x over previous
//
#include <hip/hip_runtime.h>
#include <stdint.h>

// Bert4Argument: out[b,l,c] = sum_f feat[b,l,f] * W[c,f] + b[c]
// feat = [ seq[i, head[i,l], :] | pos_emb[l - pos[i] + 256, :] | class_emb[(l==pos[i])?frame[i]:0, :] ]
// B=64, L=256, D=768 -> M=16384, K=2304, N=200 (padded to 208 = 13 tiles of 16)
//
// R2: latency-bound fix. Block = one 16-row m-tile; 4 waves split the 13
// n-tiles (wave w owns {w, w+4, w+8, w+12}). 1024 blocks * 4 waves = 4096
// waves = 16 waves/CU (was 4). acc regs 52 -> <=16, freeing the scheduler
// to pipeline loads. A-loads duplicated across the block's 4 waves but hit L1.

typedef __attribute__((ext_vector_type(8))) short short8;
typedef __attribute__((ext_vector_type(4))) float f32x4;

__device__ __forceinline__ unsigned short f2bf(float f) {
    union { float f; unsigned int u; } v; v.f = f;
    unsigned int u = v.u;
    return (unsigned short)((u + 0x7fffu + ((u >> 16) & 1u)) >> 16);
}

__device__ __forceinline__ short8 pack8(f32x4 a, f32x4 b) {
    short8 r;
    r[0] = (short)f2bf(a.x); r[1] = (short)f2bf(a.y);
    r[2] = (short)f2bf(a.z); r[3] = (short)f2bf(a.w);
    r[4] = (short)f2bf(b.x); r[5] = (short)f2bf(b.y);
    r[6] = (short)f2bf(b.z); r[7] = (short)f2bf(b.w);
    return r;
}

// ---------------------------------------------------------------------------
// Kernel 1: pack W f32 [200][2304] -> bf16 tiled layout in ws.
// Wp[(((t*288 + kb8)*16 + n)*8 + j)] = W[t*16+n][kb8*8+j]
// B-fragment read (tile t, k0): lane(quad,n) reads 16B at
//   Wp + t*36864 + (k0/8)*128*... -> 1KB contiguous per wave.
// ---------------------------------------------------------------------------
__global__ void cvt_w_kernel(const float* __restrict__ W,
                             unsigned short* __restrict__ Wp) {
    int u = blockIdx.x * 256 + threadIdx.x;          // [0, 59904)
    int n   = u & 15;
    int kb8 = (u >> 4) % 288;
    int t   = u / (288 * 16);
    int row = t * 16 + n;
    int col = kb8 * 8;
    f32x4 a = {0.f, 0.f, 0.f, 0.f}, b = {0.f, 0.f, 0.f, 0.f};
    if (row < 200) {
        const float* p = W + (size_t)row * 2304 + col;
        a = *(const f32x4*)p;
        b = *(const f32x4*)(p + 4);
    }
    short8 s = pack8(a, b);
    *(short8*)(Wp + (size_t)u * 8) = s;
}

// ---------------------------------------------------------------------------
// Kernel 2: GEMM. Grid = 1024 blocks (one 16-row m-tile each), 256 thr.
// Wave w handles n-tiles {w, w+4, w+8, w+12 (w==0 only)}.
// ---------------------------------------------------------------------------
__global__ __launch_bounds__(256) void gemm_kernel(
    const float* __restrict__ seq,   // [64,256,768]
    const float* __restrict__ pe,    // [513,768]
    const float* __restrict__ ce,    // [201,768]
    const float* __restrict__ Wf,    // [200,2304] f32 (fallback)
    const float* __restrict__ bias,  // [200]
    const int*   __restrict__ head,  // [64,256]
    const int*   __restrict__ frame, // [64]
    const int*   __restrict__ pos,   // [64]
    const unsigned short* __restrict__ Wp,  // packed bf16 W or null
    float* __restrict__ out)         // [16384,200]
{
    const int tid  = threadIdx.x;
    const int wave = tid >> 6;
    const int lane = tid & 63;
    const int n16  = lane & 15;
    const int quad = lane >> 4;

    // A-operand row this lane supplies: m = lane&15 within the block's m-tile.
    const int mrow  = blockIdx.x * 16 + n16;   // == i*256 + j
    const int i     = mrow >> 8;
    const int j     = mrow & 255;
    const int pos_i = pos[i];
    const int hi    = head[mrow];
    const int rel   = j - pos_i + 256;          // in [1, 511]
    const int cls   = (j == pos_i) ? frame[i] : 0;

    const float* segs[3];
    segs[0] = seq + ((size_t)i * 256 + (size_t)hi) * 768 + quad * 8;
    segs[1] = pe + (size_t)rel * 768 + quad * 8;
    segs[2] = ce + (size_t)cls * 768 + quad * 8;

    // n-tiles owned by this wave: t = wave + 4*u, u in [0, ntl)
    const int ntl = (wave == 0) ? 4 : 3;

    f32x4 acc[4];
#pragma unroll
    for (int u = 0; u < 4; ++u) {
        const int t = wave + 4 * u;
        const int col = t * 16 + n16;
        const float bv = (t < 13 && col < 200) ? bias[col] : 0.0f;
        acc[u] = (f32x4){bv, bv, bv, bv};
    }

    if (Wp) {
        const unsigned short* wp[4];
#pragma unroll
        for (int u = 0; u < 4; ++u) {
            const int t = (wave + 4 * u < 13) ? (wave + 4 * u) : 0;
            wp[u] = Wp + (size_t)t * 36864 + (size_t)quad * 128 + (size_t)n16 * 8;
        }

        for (int s = 0; s < 3; ++s) {
            const float* ap = segs[s];
#pragma unroll 4
            for (int kk = 0; kk < 768; kk += 32) {
                f32x4 a0 = *(const f32x4*)(ap + kk);
                f32x4 a1 = *(const f32x4*)(ap + kk + 4);
                short8 afr = pack8(a0, a1);
                const int koff = (s * 768 + kk) * 16;   // ushort offset
#pragma unroll
                for (int u = 0; u < 4; ++u) {
                    if (u < ntl) {
                        short8 bfr = *(const short8*)(wp[u] + koff);
                        acc[u] = __builtin_amdgcn_mfma_f32_16x16x32_bf16(afr, bfr, acc[u], 0, 0, 0);
                    }
                }
            }
        }
    } else {
        for (int s = 0; s < 3; ++s) {
            const float* ap = segs[s];
#pragma unroll 2
            for (int kk = 0; kk < 768; kk += 32) {
                f32x4 a0 = *(const f32x4*)(ap + kk);
                f32x4 a1 = *(const f32x4*)(ap + kk + 4);
                short8 afr = pack8(a0, a1);
                const int kglob = s * 768 + kk + quad * 8;
#pragma unroll
                for (int u = 0; u < 4; ++u) {
                    if (u < ntl) {
                        const int t = wave + 4 * u;
                        const int row = t * 16 + n16;
                        short8 bfr = {0, 0, 0, 0, 0, 0, 0, 0};
                        if (row < 200) {
                            const float* q = Wf + (size_t)row * 2304 + kglob;
                            f32x4 b0 = *(const f32x4*)q;
                            f32x4 b1 = *(const f32x4*)(q + 4);
                            bfr = pack8(b0, b1);
                        }
                        acc[u] = __builtin_amdgcn_mfma_f32_16x16x32_bf16(afr, bfr, acc[u], 0, 0, 0);
                    }
                }
            }
        }
    }

    // epilogue: C/D layout col = lane&15, row = quad*4 + r
    const int rbase = blockIdx.x * 16 + quad * 4;
#pragma unroll
    for (int u = 0; u < 4; ++u) {
        const int t = wave + 4 * u;
        if (t < 13) {
            const int col = t * 16 + n16;
            if (col < 200) {
#pragma unroll
                for (int r = 0; r < 4; ++r) {
                    out[(size_t)(rbase + r) * 200 + col] = acc[u][r];
                }
            }
        }
    }
}

// ---------------------------------------------------------------------------
extern "C" void kernel_launch(void* const* d_in, const int* in_sizes, int n_in,
                              void* d_out, int out_size, void* d_ws, size_t ws_size,
                              hipStream_t stream) {
    const float* seq  = (const float*)d_in[0];
    const float* pe   = (const float*)d_in[1];
    const float* ce   = (const float*)d_in[2];
    const float* W    = (const float*)d_in[3];
    const float* bias = (const float*)d_in[4];
    const int* head   = (const int*)d_in[5];
    const int* frame  = (const int*)d_in[6];
    const int* pos    = (const int*)d_in[7];
    float* out = (float*)d_out;

    const size_t need = (size_t)13 * 288 * 16 * 8 * sizeof(unsigned short); // 958464 B
    unsigned short* Wp = nullptr;
    if (d_ws != nullptr && ws_size >= need) {
        Wp = (unsigned short*)d_ws;
        cvt_w_kernel<<<234, 256, 0, stream>>>(W, Wp);
    }
    gemm_kernel<<<1024, 256, 0, stream>>>(seq, pe, ce, W, bias, head, frame, pos,
                                          Wp, out);
}

// Round 3
// 165.294 us; speedup vs baseline: 2.0660x; 1.0835x over previous
//
#include <hip/hip_runtime.h>
#include <stdint.h>

// Bert4Argument: out[b,l,c] = sum_f feat[b,l,f] * W[c,f] + b[c]
// feat = [ seq[i, head[i,l], :] | pos_emb[l - pos[i] + 256, :] | class_emb[(l==pos[i])?frame[i]:0, :] ]
// B=64, L=256, D=768 -> M=16384, K=2304, N=200 (13 n-tiles of 16)
//
// R3: (a) prep kernel pre-converts seq/pe/ce to bf16 + packs W into ws ->
// hot loop is pure bf16 load + MFMA (no cvt VALU). (b) block = 512 thr /
// 8 waves covering 64 rows; wave owns m-pair (2 frags) x tile-quarter
// (4/3/3/3) -> each B fragment feeds 2 MFMAs (reg reuse) and is L1-shared
// by the quarter-partner wave: L2 B-traffic 958 MB -> ~240 MB.

typedef __attribute__((ext_vector_type(8))) short short8;
typedef __attribute__((ext_vector_type(4))) float f32x4;

#define NSEQ_G 1572864   // 64*256*768/8
#define NPE_G  49248     // 513*768/8
#define NCE_G  19296     // 201*768/8
#define NW_G   59904     // 13*288*16
#define SEQB_OFF 0
#define PEB_OFF  12582912          // elems (25,165,824 B / 2)
#define CEB_OFF  (PEB_OFF + 393984)
#define WP_OFF   (CEB_OFF + 154368)
#define WS_NEED  ((size_t)(WP_OFF + 479232) * 2)   // 27,220,992 B
#define WP_ONLY_NEED ((size_t)479232 * 2)          // 958,464 B

__device__ __forceinline__ unsigned short f2bf(float f) {
    union { float f; unsigned int u; } v; v.f = f;
    unsigned int u = v.u;
    return (unsigned short)((u + 0x7fffu + ((u >> 16) & 1u)) >> 16);
}

__device__ __forceinline__ short8 pack8(f32x4 a, f32x4 b) {
    short8 r;
    r[0] = (short)f2bf(a.x); r[1] = (short)f2bf(a.y);
    r[2] = (short)f2bf(a.z); r[3] = (short)f2bf(a.w);
    r[4] = (short)f2bf(b.x); r[5] = (short)f2bf(b.y);
    r[6] = (short)f2bf(b.z); r[7] = (short)f2bf(b.w);
    return r;
}

// ---------------------------------------------------------------------------
// Prep: convert seq/pe/ce f32 -> bf16 and pack W into fragment-tiled bf16.
// Wp[(((t*288 + kb8)*16 + n)*8 + j)] = W[t*16+n][kb8*8+j]; rows >=200 zero.
// ---------------------------------------------------------------------------
__global__ void prep_kernel(const float* __restrict__ seq,
                            const float* __restrict__ pe,
                            const float* __restrict__ ce,
                            const float* __restrict__ W,
                            unsigned short* __restrict__ ws) {
    int g = blockIdx.x * 256 + threadIdx.x;
    if (g < NSEQ_G) {
        const float* p = seq + (size_t)g * 8;
        *(short8*)(ws + SEQB_OFF + (size_t)g * 8) =
            pack8(*(const f32x4*)p, *(const f32x4*)(p + 4));
        return;
    }
    g -= NSEQ_G;
    if (g < NPE_G) {
        const float* p = pe + (size_t)g * 8;
        *(short8*)(ws + PEB_OFF + (size_t)g * 8) =
            pack8(*(const f32x4*)p, *(const f32x4*)(p + 4));
        return;
    }
    g -= NPE_G;
    if (g < NCE_G) {
        const float* p = ce + (size_t)g * 8;
        *(short8*)(ws + CEB_OFF + (size_t)g * 8) =
            pack8(*(const f32x4*)p, *(const f32x4*)(p + 4));
        return;
    }
    g -= NCE_G;
    if (g < NW_G) {
        int n   = g & 15;
        int kb8 = (g >> 4) % 288;
        int t   = g / (288 * 16);
        int row = t * 16 + n;
        int col = kb8 * 8;
        f32x4 a = {0.f, 0.f, 0.f, 0.f}, b = {0.f, 0.f, 0.f, 0.f};
        if (row < 200) {
            const float* p = W + (size_t)row * 2304 + col;
            a = *(const f32x4*)p;
            b = *(const f32x4*)(p + 4);
        }
        *(short8*)(ws + WP_OFF + (size_t)g * 8) = pack8(a, b);
    }
}

// ---------------------------------------------------------------------------
// GEMM main: grid 256 blocks x 512 thr (8 waves). Block b covers rows
// [64b, 64b+64). Wave w: m-pair p=w&1 (frags 2p, 2p+1), tile-quarter q=w>>1
// owning tiles {q, q+4, q+8, q+12(q==0)}.
// ---------------------------------------------------------------------------
__global__ __launch_bounds__(512) void gemm2_kernel(
    const unsigned short* __restrict__ ws,   // seqb | peb | ceb | Wp
    const float* __restrict__ bias,
    const int*   __restrict__ head,
    const int*   __restrict__ frame,
    const int*   __restrict__ pos,
    float* __restrict__ out)
{
    const unsigned short* seqb = ws + SEQB_OFF;
    const unsigned short* peb  = ws + PEB_OFF;
    const unsigned short* ceb  = ws + CEB_OFF;
    const unsigned short* Wp   = ws + WP_OFF;

    const int tid  = threadIdx.x;
    const int wave = tid >> 6;
    const int lane = tid & 63;
    const int n16  = lane & 15;
    const int quad = lane >> 4;
    const int p    = wave & 1;
    const int q    = wave >> 2 >= 1 ? (wave >> 1) : (wave >> 1); // q = wave>>1
    const int qq   = wave >> 1;
    const int ntl  = (qq == 0) ? 4 : 3;

    const int rowbase = blockIdx.x * 64 + p * 32;

    // A segment pointers for the wave's two m-frags
    const unsigned short* aptr[2][3];
#pragma unroll
    for (int mf = 0; mf < 2; ++mf) {
        const int mrow  = rowbase + mf * 16 + n16;
        const int i     = mrow >> 8;
        const int j     = mrow & 255;
        const int pos_i = pos[i];
        const int hi    = head[mrow];
        const int rel   = j - pos_i + 256;              // [1, 511]
        const int cls   = (j == pos_i) ? frame[i] : 0;
        aptr[mf][0] = seqb + ((size_t)i * 256 + (size_t)hi) * 768 + quad * 8;
        aptr[mf][1] = peb + (size_t)rel * 768 + quad * 8;
        aptr[mf][2] = ceb + (size_t)cls * 768 + quad * 8;
    }

    // B fragment base pointers for owned tiles
    const unsigned short* bptr[4];
#pragma unroll
    for (int u = 0; u < 4; ++u) {
        int t = qq + 4 * u;
        if (t > 12) t = 0;   // u==3 unused unless qq==0
        bptr[u] = Wp + (size_t)t * 36864 + (size_t)quad * 128 + (size_t)n16 * 8;
    }

    f32x4 acc[2][4];
#pragma unroll
    for (int u = 0; u < 4; ++u) {
        const int t = qq + 4 * u;
        const int col = t * 16 + n16;
        const float bv = (t < 13 && col < 200) ? bias[col] : 0.0f;
        acc[0][u] = (f32x4){bv, 0.f, 0.f, 0.f};
        acc[0][u].y = bv; acc[0][u].z = bv; acc[0][u].w = bv;
        acc[1][u] = acc[0][u];
    }

#pragma unroll
    for (int s = 0; s < 3; ++s) {
        const unsigned short* a0 = aptr[0][s];
        const unsigned short* a1 = aptr[1][s];
        const unsigned short* b0 = bptr[0] + (size_t)s * 12288;
        const unsigned short* b1 = bptr[1] + (size_t)s * 12288;
        const unsigned short* b2 = bptr[2] + (size_t)s * 12288;
        const unsigned short* b3 = bptr[3] + (size_t)s * 12288;
#pragma unroll 4
        for (int kk = 0; kk < 768; kk += 32) {
            short8 af0 = *(const short8*)(a0 + kk);
            short8 af1 = *(const short8*)(a1 + kk);
            const int koff = kk * 16;   // ushort offset: (kk/8)*128
            {
                short8 bf = *(const short8*)(b0 + koff);
                acc[0][0] = __builtin_amdgcn_mfma_f32_16x16x32_bf16(af0, bf, acc[0][0], 0, 0, 0);
                acc[1][0] = __builtin_amdgcn_mfma_f32_16x16x32_bf16(af1, bf, acc[1][0], 0, 0, 0);
            }
            {
                short8 bf = *(const short8*)(b1 + koff);
                acc[0][1] = __builtin_amdgcn_mfma_f32_16x16x32_bf16(af0, bf, acc[0][1], 0, 0, 0);
                acc[1][1] = __builtin_amdgcn_mfma_f32_16x16x32_bf16(af1, bf, acc[1][1], 0, 0, 0);
            }
            {
                short8 bf = *(const short8*)(b2 + koff);
                acc[0][2] = __builtin_amdgcn_mfma_f32_16x16x32_bf16(af0, bf, acc[0][2], 0, 0, 0);
                acc[1][2] = __builtin_amdgcn_mfma_f32_16x16x32_bf16(af1, bf, acc[1][2], 0, 0, 0);
            }
            if (ntl == 4) {
                short8 bf = *(const short8*)(b3 + koff);
                acc[0][3] = __builtin_amdgcn_mfma_f32_16x16x32_bf16(af0, bf, acc[0][3], 0, 0, 0);
                acc[1][3] = __builtin_amdgcn_mfma_f32_16x16x32_bf16(af1, bf, acc[1][3], 0, 0, 0);
            }
        }
    }

    // epilogue: C/D layout col = lane&15, row = quad*4 + r (within 16-row frag)
#pragma unroll
    for (int mf = 0; mf < 2; ++mf) {
        const int rbase = rowbase + mf * 16 + quad * 4;
#pragma unroll
        for (int u = 0; u < 4; ++u) {
            const int t = qq + 4 * u;
            if (t < 13) {
                const int col = t * 16 + n16;
                if (col < 200) {
#pragma unroll
                    for (int r = 0; r < 4; ++r) {
                        out[(size_t)(rbase + r) * 200 + col] = acc[mf][u][r];
                    }
                }
            }
        }
    }
}

// ---------------------------------------------------------------------------
// Fallback (R2 path) if ws is too small for the bf16 mirrors.
// ---------------------------------------------------------------------------
__global__ void cvt_w_kernel(const float* __restrict__ W,
                             unsigned short* __restrict__ Wp) {
    int u = blockIdx.x * 256 + threadIdx.x;
    if (u >= NW_G) return;
    int n   = u & 15;
    int kb8 = (u >> 4) % 288;
    int t   = u / (288 * 16);
    int row = t * 16 + n;
    int col = kb8 * 8;
    f32x4 a = {0.f, 0.f, 0.f, 0.f}, b = {0.f, 0.f, 0.f, 0.f};
    if (row < 200) {
        const float* p = W + (size_t)row * 2304 + col;
        a = *(const f32x4*)p;
        b = *(const f32x4*)(p + 4);
    }
    *(short8*)(Wp + (size_t)u * 8) = pack8(a, b);
}

__global__ __launch_bounds__(256) void gemm_fallback(
    const float* __restrict__ seq, const float* __restrict__ pe,
    const float* __restrict__ ce, const float* __restrict__ Wf,
    const float* __restrict__ bias, const int* __restrict__ head,
    const int* __restrict__ frame, const int* __restrict__ pos,
    const unsigned short* __restrict__ Wp, float* __restrict__ out)
{
    const int tid  = threadIdx.x;
    const int wave = tid >> 6;
    const int lane = tid & 63;
    const int n16  = lane & 15;
    const int quad = lane >> 4;

    const int mrow  = blockIdx.x * 16 + n16;
    const int i     = mrow >> 8;
    const int j     = mrow & 255;
    const int pos_i = pos[i];
    const int hi    = head[mrow];
    const int rel   = j - pos_i + 256;
    const int cls   = (j == pos_i) ? frame[i] : 0;

    const float* segs[3];
    segs[0] = seq + ((size_t)i * 256 + (size_t)hi) * 768 + quad * 8;
    segs[1] = pe + (size_t)rel * 768 + quad * 8;
    segs[2] = ce + (size_t)cls * 768 + quad * 8;

    const int ntl = (wave == 0) ? 4 : 3;
    f32x4 acc[4];
#pragma unroll
    for (int u = 0; u < 4; ++u) {
        const int t = wave + 4 * u;
        const int col = t * 16 + n16;
        const float bv = (t < 13 && col < 200) ? bias[col] : 0.0f;
        acc[u] = (f32x4){bv, bv, bv, bv};
    }

    for (int s = 0; s < 3; ++s) {
        const float* ap = segs[s];
#pragma unroll 2
        for (int kk = 0; kk < 768; kk += 32) {
            f32x4 a0 = *(const f32x4*)(ap + kk);
            f32x4 a1 = *(const f32x4*)(ap + kk + 4);
            short8 afr = pack8(a0, a1);
#pragma unroll
            for (int u = 0; u < 4; ++u) {
                if (u < ntl) {
                    const int t = wave + 4 * u;
                    short8 bfr = {0, 0, 0, 0, 0, 0, 0, 0};
                    if (Wp) {
                        const unsigned short* wp = Wp + (size_t)t * 36864 +
                            (size_t)quad * 128 + (size_t)n16 * 8 + (size_t)(s * 768 + kk) * 16;
                        bfr = *(const short8*)wp;
                    } else {
                        const int row = t * 16 + n16;
                        if (row < 200) {
                            const float* qp = Wf + (size_t)row * 2304 + s * 768 + kk + quad * 8;
                            bfr = pack8(*(const f32x4*)qp, *(const f32x4*)(qp + 4));
                        }
                    }
                    acc[u] = __builtin_amdgcn_mfma_f32_16x16x32_bf16(afr, bfr, acc[u], 0, 0, 0);
                }
            }
        }
    }

    const int rbase = blockIdx.x * 16 + quad * 4;
#pragma unroll
    for (int u = 0; u < 4; ++u) {
        const int t = wave + 4 * u;
        if (t < 13) {
            const int col = t * 16 + n16;
            if (col < 200) {
#pragma unroll
                for (int r = 0; r < 4; ++r)
                    out[(size_t)(rbase + r) * 200 + col] = acc[u][r];
            }
        }
    }
}

// ---------------------------------------------------------------------------
extern "C" void kernel_launch(void* const* d_in, const int* in_sizes, int n_in,
                              void* d_out, int out_size, void* d_ws, size_t ws_size,
                              hipStream_t stream) {
    const float* seq  = (const float*)d_in[0];
    const float* pe   = (const float*)d_in[1];
    const float* ce   = (const float*)d_in[2];
    const float* W    = (const float*)d_in[3];
    const float* bias = (const float*)d_in[4];
    const int* head   = (const int*)d_in[5];
    const int* frame  = (const int*)d_in[6];
    const int* pos    = (const int*)d_in[7];
    float* out = (float*)d_out;

    if (d_ws != nullptr && ws_size >= WS_NEED) {
        unsigned short* ws = (unsigned short*)d_ws;
        const int total_g = NSEQ_G + NPE_G + NCE_G + NW_G;   // 1,701,312
        prep_kernel<<<(total_g + 255) / 256, 256, 0, stream>>>(seq, pe, ce, W, ws);
        gemm2_kernel<<<256, 512, 0, stream>>>(ws, bias, head, frame, pos, out);
    } else {
        unsigned short* Wp = nullptr;
        if (d_ws != nullptr && ws_size >= WP_ONLY_NEED) {
            Wp = (unsigned short*)d_ws;
            cvt_w_kernel<<<(NW_G + 255) / 256, 256, 0, stream>>>(W, Wp);
        }
        gemm_fallback<<<1024, 256, 0, stream>>>(seq, pe, ce, W, bias, head,
                                                frame, pos, Wp, out);
    }
}